// Round 8
// baseline (326.193 us; speedup 1.0000x reference)
//
#include <hip/hip_runtime.h>

// ComplexSKPDELayer — MFMA formulation (R8).
// R7 -> R8: register-pressure restructure. R5/R7 both pinned at ~17%
// occupancy regardless of grid: 40 live f4 accumulators (160 regs) + 128
// VGPRs ~= 288/wave -> 1-2 waves/SIMD on the unified gfx950 file. Fix:
// c-outer / s-inner loop nest -> only 5 accumulators (20 regs) live at a
// time; A-frags precomputed per tile (20 H8 = 80 VGPRs). launch_bounds
// (512,4) caps VGPR at 128 -> 4 waves/SIMD = 16 waves/CU. Epilogue fused:
// v_k = lap_k + 4*h2_k -> 2 running sums, half the shfl reduction.
// Grid 512 x block 512: 2 blocks/CU, uniform 4 interior + 1 bc tile/wave.
// Math (per 16-point tile, 5 A-row-tiles h/gx/gy/gz/s through W2):
//   h1=tanh(z1), d1=1-h1^2, g1a=d1*W1[a,:], s1=(-2q)*h1*d1, q=sum_a W1[a,:]^2
//   C=A@W2 -> z2,ux,uy,uz,t; h2=tanh(z2+b2), lap_k=d2*(t-2*h2*sum u^2)
//   helm = lap + 4*y; re stored at out[2+p], losses atomically into out[0..1].

#define N_INT 262144
#define N_BC  65536
#define HID   128
#define GRID  512
#define WPB   8                      // waves per 512-thread block
#define NWAVE (GRID * WPB)           // 4096 waves
#define TILES_INT (N_INT / 16)       // 16384 -> 4 per wave
#define TILES_BC  (N_BC / 16)        // 4096  -> 1 per wave
#define TILES_ALL (TILES_INT + TILES_BC)

typedef _Float16 h8  __attribute__((ext_vector_type(8)));
typedef __fp16   h2t __attribute__((ext_vector_type(2)));   // cvt_pkrtz result type
typedef float    f4  __attribute__((ext_vector_type(4)));

union H8 { h8 v; h2t p[4]; };

__device__ __forceinline__ float ftanh(float x) {
    // tanh(x) = 1 - 2/(e^{2x}+1); v_exp_f32 + v_rcp_f32, ~2 ulp, inf-safe
    float e = __expf(2.0f * x);
    return 1.0f - 2.0f * __builtin_amdgcn_rcpf(e + 1.0f);
}

extern "C" __global__ __launch_bounds__(512, 4)
void pde_mfma(const float* __restrict__ ci, const float* __restrict__ cb,
              const float* __restrict__ gt, const float* __restrict__ latent,
              const float* __restrict__ W1, const float* __restrict__ b1,
              const float* __restrict__ W2, const float* __restrict__ b2,
              const float* __restrict__ W3, const float* __restrict__ b3,
              float* __restrict__ out)
{
    // B-frag pack: sB[(((s*8+c)*64)+lane)*8+i] = fp16 W2[s*32+(lane>>4)*8+i][c*16+(lane&15)]
    __shared__ _Float16 sB[4 * 8 * 64 * 8];        // 32 KiB
    __shared__ float sWx[HID], sWy[HID], sWz[HID], sC1[HID], sQ2[HID];
    __shared__ float sB2[HID];
    __shared__ float2 sW3[HID];

    const int tid = threadIdx.x;

    // ---- one-time per-block prep ----
    for (int e = 0; e < 32; ++e) {
        int idx = e * 512 + tid;                   // coalesced over W2 row-major
        int j = idx >> 7, n = idx & 127;           // j = K row, n = out col
        int s = j >> 5, qd = (j >> 3) & 3, i = j & 7;
        int c = n >> 4,  nn = n & 15;
        sB[(((s * 8 + c) * 64) + (qd * 16 + nn)) * 8 + i] = (_Float16)W2[idx];
    }
    if (tid < HID) {
        float acc = b1[tid];
        for (int l = 0; l < 64; ++l)
            acc = fmaf(latent[l], W1[(3 + l) * HID + tid], acc);
        sC1[tid] = acc;
        float wx = W1[tid], wy = W1[HID + tid], wz = W1[2 * HID + tid];
        sWx[tid] = wx; sWy[tid] = wy; sWz[tid] = wz;
        sQ2[tid] = -2.0f * fmaf(wx, wx, fmaf(wy, wy, wz * wz));
        sB2[tid] = b2[tid];
        sW3[tid] = ((const float2*)W3)[tid];
    }
    __syncthreads();

    const int lane = tid & 63;
    const int m    = lane & 15;        // point-in-tile (A row / C col)
    const int qd   = lane >> 4;        // quad: k-subrange / C row block
    const int wgid = blockIdx.x * WPB + (tid >> 6);
    const float b30 = b3[0], b31 = b3[1];
    const f4 z4 = {0.0f, 0.0f, 0.0f, 0.0f};

    float lsum = 0.0f, bsum = 0.0f;

    for (int t = wgid; t < TILES_ALL; t += NWAVE) {
      if (t < TILES_INT) {
        // ================= interior tile: 16 points =================
        const int p0 = t * 16;
        const int pt = p0 + m;
        const float x = ci[3 * pt], y = ci[3 * pt + 1], z = ci[3 * pt + 2];

        // ---- phase 1: A-fragments for all 4 K-chunks (held in VGPRs) ----
        H8 Fh[4], Fx[4], Fy[4], Fz[4], Ft[4];
        #pragma unroll
        for (int s = 0; s < 4; ++s) {
            const int j0 = s * 32 + qd * 8;
            #pragma unroll
            for (int ii = 0; ii < 4; ++ii) {
                const int j = j0 + 2 * ii;
                float wxa = sWx[j],     wya = sWy[j],     wza = sWz[j];
                float wxb = sWx[j + 1], wyb = sWy[j + 1], wzb = sWz[j + 1];
                float za = fmaf(x, wxa, fmaf(y, wya, fmaf(z, wza, sC1[j])));
                float zb = fmaf(x, wxb, fmaf(y, wyb, fmaf(z, wzb, sC1[j + 1])));
                float ha = ftanh(za), hb = ftanh(zb);
                float da = fmaf(-ha, ha, 1.0f), db = fmaf(-hb, hb, 1.0f);
                Fh[s].p[ii] = __builtin_amdgcn_cvt_pkrtz(ha, hb);
                Fx[s].p[ii] = __builtin_amdgcn_cvt_pkrtz(da * wxa, db * wxb);
                Fy[s].p[ii] = __builtin_amdgcn_cvt_pkrtz(da * wya, db * wyb);
                Fz[s].p[ii] = __builtin_amdgcn_cvt_pkrtz(da * wza, db * wzb);
                Ft[s].p[ii] = __builtin_amdgcn_cvt_pkrtz(sQ2[j] * ha * da,
                                                         sQ2[j + 1] * hb * db);
            }
        }

        // ---- c-outer: one 16-col output block at a time (5 live accums) ----
        float rr[4] = {0,0,0,0}, ri[4] = {0,0,0,0};
        #pragma unroll
        for (int c = 0; c < 8; ++c) {
            float b2k = sB2[c * 16 + m];           // fold b2 into z2 accum
            f4 aZ = (f4){b2k, b2k, b2k, b2k};
            f4 aX = z4, aY = z4, aW = z4, aT = z4;
            #pragma unroll
            for (int s = 0; s < 4; ++s) {
                h8 bf = *(const h8*)&sB[(((s * 8 + c) * 64) + lane) * 8];
                aZ = __builtin_amdgcn_mfma_f32_16x16x32_f16(Fh[s].v, bf, aZ, 0, 0, 0);
                aX = __builtin_amdgcn_mfma_f32_16x16x32_f16(Fx[s].v, bf, aX, 0, 0, 0);
                aY = __builtin_amdgcn_mfma_f32_16x16x32_f16(Fy[s].v, bf, aY, 0, 0, 0);
                aW = __builtin_amdgcn_mfma_f32_16x16x32_f16(Fz[s].v, bf, aW, 0, 0, 0);
                aT = __builtin_amdgcn_mfma_f32_16x16x32_f16(Ft[s].v, bf, aT, 0, 0, 0);
            }
            const float2 w3 = sW3[c * 16 + m];
            #pragma unroll
            for (int r = 0; r < 4; ++r) {          // point = qd*4 + r
                float h2 = ftanh(aZ[r]);
                float d2 = fmaf(-h2, h2, 1.0f);
                float uu = fmaf(aX[r], aX[r], fmaf(aY[r], aY[r], aW[r] * aW[r]));
                float lk = d2 * fmaf(-2.0f * h2, uu, aT[r]);
                float vk = fmaf(4.0f, h2, lk);     // lap_k + K^2*h2_k
                rr[r] = fmaf(vk, w3.x, rr[r]);
                ri[r] = fmaf(vk, w3.y, ri[r]);
            }
        }
        #pragma unroll
        for (int off = 1; off <= 8; off <<= 1) {   // reduce over k-lanes (m)
            #pragma unroll
            for (int r = 0; r < 4; ++r) {
                rr[r] += __shfl_xor(rr[r], off);
                ri[r] += __shfl_xor(ri[r], off);
            }
        }
        if (m == 0) {
            #pragma unroll
            for (int r = 0; r < 4; ++r) {
                float re = fmaf(4.0f, b30, rr[r]);
                float im = fmaf(4.0f, b31, ri[r]);
                out[2 + p0 + qd * 4 + r] = re;
                lsum = fmaf(re, re, fmaf(im, im, lsum));
            }
        }
      } else {
        // ================= boundary tile: 16 points, forward only =================
        const int q0 = (t - TILES_INT) * 16;
        const int pt = q0 + m;
        const float x = cb[3 * pt], y = cb[3 * pt + 1], z = cb[3 * pt + 2];

        H8 Fh[4];
        #pragma unroll
        for (int s = 0; s < 4; ++s) {
            const int j0 = s * 32 + qd * 8;
            #pragma unroll
            for (int ii = 0; ii < 4; ++ii) {
                const int j = j0 + 2 * ii;
                float za = fmaf(x, sWx[j],     fmaf(y, sWy[j],     fmaf(z, sWz[j],     sC1[j])));
                float zb = fmaf(x, sWx[j + 1], fmaf(y, sWy[j + 1], fmaf(z, sWz[j + 1], sC1[j + 1])));
                Fh[s].p[ii] = __builtin_amdgcn_cvt_pkrtz(ftanh(za), ftanh(zb));
            }
        }

        float yr[4] = {0,0,0,0}, yi[4] = {0,0,0,0};
        #pragma unroll
        for (int c = 0; c < 8; ++c) {
            float b2k = sB2[c * 16 + m];
            f4 aZ = (f4){b2k, b2k, b2k, b2k};
            #pragma unroll
            for (int s = 0; s < 4; ++s) {
                h8 bf = *(const h8*)&sB[(((s * 8 + c) * 64) + lane) * 8];
                aZ = __builtin_amdgcn_mfma_f32_16x16x32_f16(Fh[s].v, bf, aZ, 0, 0, 0);
            }
            const float2 w3 = sW3[c * 16 + m];
            #pragma unroll
            for (int r = 0; r < 4; ++r) {
                float h2 = ftanh(aZ[r]);
                yr[r] = fmaf(h2, w3.x, yr[r]);
                yi[r] = fmaf(h2, w3.y, yi[r]);
            }
        }
        #pragma unroll
        for (int off = 1; off <= 8; off <<= 1) {
            #pragma unroll
            for (int r = 0; r < 4; ++r) {
                yr[r] += __shfl_xor(yr[r], off);
                yi[r] += __shfl_xor(yi[r], off);
            }
        }
        if (m == 0) {
            #pragma unroll
            for (int r = 0; r < 4; ++r) {
                float dr = yr[r] + b30 - gt[q0 + qd * 4 + r];
                float di = yi[r] + b31;
                bsum = fmaf(dr, dr, fmaf(di, di, bsum));
            }
        }
      }
    }

    // wave-wide loss reduction, one atomic per wave
    #pragma unroll
    for (int off = 1; off < 64; off <<= 1) {
        lsum += __shfl_xor(lsum, off);
        bsum += __shfl_xor(bsum, off);
    }
    if (lane == 0) {
        atomicAdd(out,     lsum * (1.0f / (float)N_INT));
        atomicAdd(out + 1, bsum * (1.0f / (float)N_BC));
    }
}

extern "C" void kernel_launch(void* const* d_in, const int* in_sizes, int n_in,
                              void* d_out, int out_size, void* d_ws, size_t ws_size,
                              hipStream_t stream)
{
    const float* ci  = (const float*)d_in[0];   // coords_int (262144,3)
    const float* cb  = (const float*)d_in[1];   // coords_bc  (65536,3)
    const float* gt  = (const float*)d_in[2];   // gt_bc      (65536,1)
    const float* lat = (const float*)d_in[3];   // latent     (64,)
    const float* W1  = (const float*)d_in[4];   // (67,128)
    const float* b1  = (const float*)d_in[5];   // (128,)
    const float* W2  = (const float*)d_in[6];   // (128,128)
    const float* b2  = (const float*)d_in[7];   // (128,)
    const float* W3  = (const float*)d_in[8];   // (128,2)
    const float* b3  = (const float*)d_in[9];   // (2,)
    float* out = (float*)d_out;   // [loss_pde, loss_bc, re(helm)*N_INT]

    // zero the two loss accumulators (out is poisoned 0xAA before every call)
    (void)hipMemsetAsync(d_out, 0, 2 * sizeof(float), stream);

    hipLaunchKernelGGL(pde_mfma, dim3(GRID), dim3(512), 0, stream,
                       ci, cb, gt, lat, W1, b1, W2, b2, W3, b3, out);
}

// Round 9
// 208.106 us; speedup vs baseline: 1.5674x; 1.5674x over previous
//
#include <hip/hip_runtime.h>

// ComplexSKPDELayer — MFMA formulation (R9).
// R8 -> R9: same c-outer structure, launch_bounds(512,4) -> (512,2).
// R8's forced 4 waves/SIMD capped the UNIFIED reg file at 512/4=128 regs
// (VGPR+AGPR combined on gfx950) for a kernel with ~160 live -> massive
// scratch spills (hbm_bytes 13 MB -> 864 MB, HBM 41% peak, VALUBusy 17%).
// (512,2) gives a 256-reg cap: no spill, 2 waves/SIMD = 8 waves/CU —
// still 1.5x R5/R7's residency (those were reg-capped at 1.35 waves/SIMD
// by 128 VGPR + 160 AGPR ≈ 288 > 512/2).
// Math (per 16-point tile, 5 A-row-tiles h/gx/gy/gz/s through W2):
//   h1=tanh(z1), d1=1-h1^2, g1a=d1*W1[a,:], s1=(-2q)*h1*d1, q=sum_a W1[a,:]^2
//   C=A@W2 -> z2,ux,uy,uz,t; h2=tanh(z2+b2), lap_k=d2*(t-2*h2*sum u^2)
//   helm = lap + 4*y; re stored at out[2+p], losses atomically into out[0..1].

#define N_INT 262144
#define N_BC  65536
#define HID   128
#define GRID  512
#define WPB   8                      // waves per 512-thread block
#define NWAVE (GRID * WPB)           // 4096 waves
#define TILES_INT (N_INT / 16)       // 16384 -> 4 per wave
#define TILES_BC  (N_BC / 16)        // 4096  -> 1 per wave
#define TILES_ALL (TILES_INT + TILES_BC)

typedef _Float16 h8  __attribute__((ext_vector_type(8)));
typedef __fp16   h2t __attribute__((ext_vector_type(2)));   // cvt_pkrtz result type
typedef float    f4  __attribute__((ext_vector_type(4)));

union H8 { h8 v; h2t p[4]; };

__device__ __forceinline__ float ftanh(float x) {
    // tanh(x) = 1 - 2/(e^{2x}+1); v_exp_f32 + v_rcp_f32, ~2 ulp, inf-safe
    float e = __expf(2.0f * x);
    return 1.0f - 2.0f * __builtin_amdgcn_rcpf(e + 1.0f);
}

extern "C" __global__ __launch_bounds__(512, 2)
void pde_mfma(const float* __restrict__ ci, const float* __restrict__ cb,
              const float* __restrict__ gt, const float* __restrict__ latent,
              const float* __restrict__ W1, const float* __restrict__ b1,
              const float* __restrict__ W2, const float* __restrict__ b2,
              const float* __restrict__ W3, const float* __restrict__ b3,
              float* __restrict__ out)
{
    // B-frag pack: sB[(((s*8+c)*64)+lane)*8+i] = fp16 W2[s*32+(lane>>4)*8+i][c*16+(lane&15)]
    __shared__ _Float16 sB[4 * 8 * 64 * 8];        // 32 KiB
    __shared__ float sWx[HID], sWy[HID], sWz[HID], sC1[HID], sQ2[HID];
    __shared__ float sB2[HID];
    __shared__ float2 sW3[HID];

    const int tid = threadIdx.x;

    // ---- one-time per-block prep ----
    for (int e = 0; e < 32; ++e) {
        int idx = e * 512 + tid;                   // coalesced over W2 row-major
        int j = idx >> 7, n = idx & 127;           // j = K row, n = out col
        int s = j >> 5, qd = (j >> 3) & 3, i = j & 7;
        int c = n >> 4,  nn = n & 15;
        sB[(((s * 8 + c) * 64) + (qd * 16 + nn)) * 8 + i] = (_Float16)W2[idx];
    }
    if (tid < HID) {
        float acc = b1[tid];
        for (int l = 0; l < 64; ++l)
            acc = fmaf(latent[l], W1[(3 + l) * HID + tid], acc);
        sC1[tid] = acc;
        float wx = W1[tid], wy = W1[HID + tid], wz = W1[2 * HID + tid];
        sWx[tid] = wx; sWy[tid] = wy; sWz[tid] = wz;
        sQ2[tid] = -2.0f * fmaf(wx, wx, fmaf(wy, wy, wz * wz));
        sB2[tid] = b2[tid];
        sW3[tid] = ((const float2*)W3)[tid];
    }
    __syncthreads();

    const int lane = tid & 63;
    const int m    = lane & 15;        // point-in-tile (A row / C col)
    const int qd   = lane >> 4;        // quad: k-subrange / C row block
    const int wgid = blockIdx.x * WPB + (tid >> 6);
    const float b30 = b3[0], b31 = b3[1];
    const f4 z4 = {0.0f, 0.0f, 0.0f, 0.0f};

    float lsum = 0.0f, bsum = 0.0f;

    for (int t = wgid; t < TILES_ALL; t += NWAVE) {
      if (t < TILES_INT) {
        // ================= interior tile: 16 points =================
        const int p0 = t * 16;
        const int pt = p0 + m;
        const float x = ci[3 * pt], y = ci[3 * pt + 1], z = ci[3 * pt + 2];

        // ---- phase 1: A-fragments for all 4 K-chunks (held in VGPRs) ----
        H8 Fh[4], Fx[4], Fy[4], Fz[4], Ft[4];
        #pragma unroll
        for (int s = 0; s < 4; ++s) {
            const int j0 = s * 32 + qd * 8;
            #pragma unroll
            for (int ii = 0; ii < 4; ++ii) {
                const int j = j0 + 2 * ii;
                float wxa = sWx[j],     wya = sWy[j],     wza = sWz[j];
                float wxb = sWx[j + 1], wyb = sWy[j + 1], wzb = sWz[j + 1];
                float za = fmaf(x, wxa, fmaf(y, wya, fmaf(z, wza, sC1[j])));
                float zb = fmaf(x, wxb, fmaf(y, wyb, fmaf(z, wzb, sC1[j + 1])));
                float ha = ftanh(za), hb = ftanh(zb);
                float da = fmaf(-ha, ha, 1.0f), db = fmaf(-hb, hb, 1.0f);
                Fh[s].p[ii] = __builtin_amdgcn_cvt_pkrtz(ha, hb);
                Fx[s].p[ii] = __builtin_amdgcn_cvt_pkrtz(da * wxa, db * wxb);
                Fy[s].p[ii] = __builtin_amdgcn_cvt_pkrtz(da * wya, db * wyb);
                Fz[s].p[ii] = __builtin_amdgcn_cvt_pkrtz(da * wza, db * wzb);
                Ft[s].p[ii] = __builtin_amdgcn_cvt_pkrtz(sQ2[j] * ha * da,
                                                         sQ2[j + 1] * hb * db);
            }
        }

        // ---- c-outer: one 16-col output block at a time (5 live accums) ----
        float rr[4] = {0,0,0,0}, ri[4] = {0,0,0,0};
        #pragma unroll
        for (int c = 0; c < 8; ++c) {
            float b2k = sB2[c * 16 + m];           // fold b2 into z2 accum
            f4 aZ = (f4){b2k, b2k, b2k, b2k};
            f4 aX = z4, aY = z4, aW = z4, aT = z4;
            #pragma unroll
            for (int s = 0; s < 4; ++s) {
                h8 bf = *(const h8*)&sB[(((s * 8 + c) * 64) + lane) * 8];
                aZ = __builtin_amdgcn_mfma_f32_16x16x32_f16(Fh[s].v, bf, aZ, 0, 0, 0);
                aX = __builtin_amdgcn_mfma_f32_16x16x32_f16(Fx[s].v, bf, aX, 0, 0, 0);
                aY = __builtin_amdgcn_mfma_f32_16x16x32_f16(Fy[s].v, bf, aY, 0, 0, 0);
                aW = __builtin_amdgcn_mfma_f32_16x16x32_f16(Fz[s].v, bf, aW, 0, 0, 0);
                aT = __builtin_amdgcn_mfma_f32_16x16x32_f16(Ft[s].v, bf, aT, 0, 0, 0);
            }
            const float2 w3 = sW3[c * 16 + m];
            #pragma unroll
            for (int r = 0; r < 4; ++r) {          // point = qd*4 + r
                float h2 = ftanh(aZ[r]);
                float d2 = fmaf(-h2, h2, 1.0f);
                float uu = fmaf(aX[r], aX[r], fmaf(aY[r], aY[r], aW[r] * aW[r]));
                float lk = d2 * fmaf(-2.0f * h2, uu, aT[r]);
                float vk = fmaf(4.0f, h2, lk);     // lap_k + K^2*h2_k
                rr[r] = fmaf(vk, w3.x, rr[r]);
                ri[r] = fmaf(vk, w3.y, ri[r]);
            }
        }
        #pragma unroll
        for (int off = 1; off <= 8; off <<= 1) {   // reduce over k-lanes (m)
            #pragma unroll
            for (int r = 0; r < 4; ++r) {
                rr[r] += __shfl_xor(rr[r], off);
                ri[r] += __shfl_xor(ri[r], off);
            }
        }
        if (m == 0) {
            #pragma unroll
            for (int r = 0; r < 4; ++r) {
                float re = fmaf(4.0f, b30, rr[r]);
                float im = fmaf(4.0f, b31, ri[r]);
                out[2 + p0 + qd * 4 + r] = re;
                lsum = fmaf(re, re, fmaf(im, im, lsum));
            }
        }
      } else {
        // ================= boundary tile: 16 points, forward only =================
        const int q0 = (t - TILES_INT) * 16;
        const int pt = q0 + m;
        const float x = cb[3 * pt], y = cb[3 * pt + 1], z = cb[3 * pt + 2];

        H8 Fh[4];
        #pragma unroll
        for (int s = 0; s < 4; ++s) {
            const int j0 = s * 32 + qd * 8;
            #pragma unroll
            for (int ii = 0; ii < 4; ++ii) {
                const int j = j0 + 2 * ii;
                float za = fmaf(x, sWx[j],     fmaf(y, sWy[j],     fmaf(z, sWz[j],     sC1[j])));
                float zb = fmaf(x, sWx[j + 1], fmaf(y, sWy[j + 1], fmaf(z, sWz[j + 1], sC1[j + 1])));
                Fh[s].p[ii] = __builtin_amdgcn_cvt_pkrtz(ftanh(za), ftanh(zb));
            }
        }

        float yr[4] = {0,0,0,0}, yi[4] = {0,0,0,0};
        #pragma unroll
        for (int c = 0; c < 8; ++c) {
            float b2k = sB2[c * 16 + m];
            f4 aZ = (f4){b2k, b2k, b2k, b2k};
            #pragma unroll
            for (int s = 0; s < 4; ++s) {
                h8 bf = *(const h8*)&sB[(((s * 8 + c) * 64) + lane) * 8];
                aZ = __builtin_amdgcn_mfma_f32_16x16x32_f16(Fh[s].v, bf, aZ, 0, 0, 0);
            }
            const float2 w3 = sW3[c * 16 + m];
            #pragma unroll
            for (int r = 0; r < 4; ++r) {
                float h2 = ftanh(aZ[r]);
                yr[r] = fmaf(h2, w3.x, yr[r]);
                yi[r] = fmaf(h2, w3.y, yi[r]);
            }
        }
        #pragma unroll
        for (int off = 1; off <= 8; off <<= 1) {
            #pragma unroll
            for (int r = 0; r < 4; ++r) {
                yr[r] += __shfl_xor(yr[r], off);
                yi[r] += __shfl_xor(yi[r], off);
            }
        }
        if (m == 0) {
            #pragma unroll
            for (int r = 0; r < 4; ++r) {
                float dr = yr[r] + b30 - gt[q0 + qd * 4 + r];
                float di = yi[r] + b31;
                bsum = fmaf(dr, dr, fmaf(di, di, bsum));
            }
        }
      }
    }

    // wave-wide loss reduction, one atomic per wave
    #pragma unroll
    for (int off = 1; off < 64; off <<= 1) {
        lsum += __shfl_xor(lsum, off);
        bsum += __shfl_xor(bsum, off);
    }
    if (lane == 0) {
        atomicAdd(out,     lsum * (1.0f / (float)N_INT));
        atomicAdd(out + 1, bsum * (1.0f / (float)N_BC));
    }
}

extern "C" void kernel_launch(void* const* d_in, const int* in_sizes, int n_in,
                              void* d_out, int out_size, void* d_ws, size_t ws_size,
                              hipStream_t stream)
{
    const float* ci  = (const float*)d_in[0];   // coords_int (262144,3)
    const float* cb  = (const float*)d_in[1];   // coords_bc  (65536,3)
    const float* gt  = (const float*)d_in[2];   // gt_bc      (65536,1)
    const float* lat = (const float*)d_in[3];   // latent     (64,)
    const float* W1  = (const float*)d_in[4];   // (67,128)
    const float* b1  = (const float*)d_in[5];   // (128,)
    const float* W2  = (const float*)d_in[6];   // (128,128)
    const float* b2  = (const float*)d_in[7];   // (128,)
    const float* W3  = (const float*)d_in[8];   // (128,2)
    const float* b3  = (const float*)d_in[9];   // (2,)
    float* out = (float*)d_out;   // [loss_pde, loss_bc, re(helm)*N_INT]

    // zero the two loss accumulators (out is poisoned 0xAA before every call)
    (void)hipMemsetAsync(d_out, 0, 2 * sizeof(float), stream);

    hipLaunchKernelGGL(pde_mfma, dim3(GRID), dim3(512), 0, stream,
                       ci, cb, gt, lat, W1, b1, W2, b2, W3, b3, out);
}